// Round 1
// baseline (1222.372 us; speedup 1.0000x reference)
//
#include <hip/hip_runtime.h>

#define N_LOC 500000
#define C 128
#define A 24
#define AC 152          // A + C
#define H 256
#define X 128
#define G3 768          // 3*H
#define GRID_BIG 1024
#define MSCALE 64.0f    // contents stored as fp8(e4m3) of 64*value (dodges denorm cliff)
#define MINV 0.015625f  // 1/64

typedef unsigned short ushort_t;
typedef unsigned char uchar_t;
typedef float floatx2 __attribute__((ext_vector_type(2)));

__device__ __forceinline__ float sigmoidf_(float x) { return 1.0f / (1.0f + __expf(-x)); }

// bf16 pack/unpack (RNE; inputs finite) -- used for addresses
__device__ __forceinline__ ushort_t f2bf(float f) {
    unsigned u = __float_as_uint(f);
    u += 0x7FFFu + ((u >> 16) & 1u);
    return (ushort_t)(u >> 16);
}
__device__ __forceinline__ float bf2f(ushort_t s) {
    return __uint_as_float(((unsigned)s) << 16);
}

// ---- OCP e4m3fn helpers (HW cvt if available, bit-exact SW fallback) ----
#if defined(__has_builtin)
#if __has_builtin(__builtin_amdgcn_cvt_pk_fp8_f32) && __has_builtin(__builtin_amdgcn_cvt_pk_f32_fp8)
#define HAVE_HW_FP8 1
#endif
#endif

__device__ __forceinline__ unsigned f2fp8_sw(float f) {   // RNE encode, pre-scaled input
    unsigned sgn = (__float_as_uint(f) >> 24) & 0x80u;
    float af = fminf(fabsf(f), 448.0f);
    unsigned q;
    if (af < 0.015625f) {                       // denormal band: round(v*512), 8 rolls into min-normal
        q = (unsigned)__float2int_rn(af * 512.0f);
    } else {
        unsigned a = __float_as_uint(af);
        a += 0x7FFFFu + ((a >> 20) & 1u);       // RNE into 3-bit mantissa
        unsigned e = (a >> 23) - 120u;
        q = (e << 3) | ((a >> 20) & 7u);
        if (q > 126u) q = 126u;                 // clamp at 448, never emit NaN code
    }
    return q | sgn;
}
__device__ __forceinline__ float fp8d_sw(unsigned b) {
    unsigned sgn = (b & 0x80u) << 24;
    unsigned e = (b >> 3) & 15u;
    unsigned m = b & 7u;
    float fn = __uint_as_float(sgn | ((e + 120u) << 23) | (m << 20));
    float fd = __uint_as_float(sgn | __float_as_uint((float)m * 0.001953125f));
    return e ? fn : fd;
}
__device__ __forceinline__ unsigned pack_fp8x4(float4 m) {
#ifdef HAVE_HW_FP8
    int w = 0;
    w = __builtin_amdgcn_cvt_pk_fp8_f32(m.x, m.y, w, false);
    w = __builtin_amdgcn_cvt_pk_fp8_f32(m.z, m.w, w, true);
    return (unsigned)w;
#else
    return f2fp8_sw(m.x) | (f2fp8_sw(m.y) << 8) | (f2fp8_sw(m.z) << 16) | (f2fp8_sw(m.w) << 24);
#endif
}
__device__ __forceinline__ float4 unpack_fp8x4(unsigned w) {
#ifdef HAVE_HW_FP8
    floatx2 lo = __builtin_amdgcn_cvt_pk_f32_fp8((int)w, false);
    floatx2 hi = __builtin_amdgcn_cvt_pk_f32_fp8((int)w, true);
    return make_float4(lo[0], lo[1], hi[0], hi[1]);
#else
    return make_float4(fp8d_sw(w & 255u), fp8d_sw((w >> 8) & 255u),
                       fp8d_sw((w >> 16) & 255u), fp8d_sw(w >> 24));
#endif
}

// ---------------------------------------------------------------------------
// Big streaming pass over N_LOC x C memory. Contents cached as fp8 (x64
// scaled domain), addresses as bf16. mem_t recomputed on the fly from the
// pristine cached copy + per-step scalars. part is TRANSPOSED: [132][1024].
// ---------------------------------------------------------------------------
template <int NPREV, bool WRITE_E, bool CONVERT>
__global__ __launch_bounds__(256) void big_pass(
    const float* __restrict__ mem0, const float* __restrict__ addr,
    uchar_t* __restrict__ memq, ushort_t* __restrict__ addrbf,
    const float* __restrict__ qacc,   // [153]: q[0..151], raw sharpen at [152]
    const float* __restrict__ ehist,  // [5][128] raw erase pre-sigmoid
    const float* __restrict__ chist,  // [5][128] raw cand pre-relu
    const float* __restrict__ ssum4,  // [8]: softmax denom of step s
    const float* __restrict__ earr,   // [3][N_LOC] raw exp values per step
    float* __restrict__ enew,         // e output for this step (if WRITE_E)
    float* __restrict__ part)         // [132][GRID_BIG] partials (content rows | denom row)
{
    const int lane = threadIdx.x & 31;   // column group: 4 elements each
    const int rg   = threadIdx.x >> 5;   // row group 0..7

    float4 qc = *(const float4*)(qacc + A + 4 * lane);
    qc.x *= MINV; qc.y *= MINV; qc.z *= MINV; qc.w *= MINV;  // fold 1/64 (m is x64)
    float4 qa = make_float4(0.f, 0.f, 0.f, 0.f);
    if (lane < 6) qa = *(const float4*)(qacc + 4 * lane);
    float beta;
    { float t = qacc[AC]; beta = (t > 20.f ? t : log1pf(__expf(t))) + 1.0f; }

    constexpr int NP = (NPREV > 0) ? NPREV : 1;
    float4 er[NP], cd[NP];
    float inv_s[NP];
#pragma unroll
    for (int s = 0; s < NPREV; ++s) {
        float4 et = *(const float4*)(ehist + (s + 1) * C + 4 * lane);
        er[s].x = sigmoidf_(et.x); er[s].y = sigmoidf_(et.y);
        er[s].z = sigmoidf_(et.z); er[s].w = sigmoidf_(et.w);
        float4 ct = *(const float4*)(chist + (s + 1) * C + 4 * lane);
        cd[s].x = fmaxf(ct.x, 0.f) * MSCALE;  // cand in scaled domain
        cd[s].y = fmaxf(ct.y, 0.f) * MSCALE;
        cd[s].z = fmaxf(ct.z, 0.f) * MSCALE;
        cd[s].w = fmaxf(ct.w, 0.f) * MSCALE;
        inv_s[s] = 1.0f / ssum4[s + 1];
    }

    float4 acc = make_float4(0.f, 0.f, 0.f, 0.f);
    float sumloc = 0.f;
    const int stride = gridDim.x * 8;

    for (int i = blockIdx.x * 8 + rg; i < N_LOC; i += stride) {
        float4 m, a4 = make_float4(0.f, 0.f, 0.f, 0.f);
        if (CONVERT) {
            float4 mf = *(const float4*)(mem0 + (size_t)i * C + 4 * lane);
            m.x = mf.x * MSCALE; m.y = mf.y * MSCALE;
            m.z = mf.z * MSCALE; m.w = mf.w * MSCALE;
            *(unsigned*)(memq + (size_t)i * C + 4 * lane) = pack_fp8x4(m);
            if (lane < 6) {
                a4 = *(const float4*)(addr + (size_t)i * A + 4 * lane);
                ushort4 au; au.x = f2bf(a4.x); au.y = f2bf(a4.y);
                au.z = f2bf(a4.z); au.w = f2bf(a4.w);
                *(ushort4*)(addrbf + (size_t)i * A + 4 * lane) = au;
            }
        } else {
            unsigned mw = *(const unsigned*)(memq + (size_t)i * C + 4 * lane);
            m = unpack_fp8x4(mw);  // scaled domain (64x)
            if (lane < 6) {
                ushort4 au = *(const ushort4*)(addrbf + (size_t)i * A + 4 * lane);
                a4 = make_float4(bf2f(au.x), bf2f(au.y), bf2f(au.z), bf2f(au.w));
            }
        }

#pragma unroll
        for (int s = 0; s < NPREV; ++s) {
            float w = earr[s * N_LOC + i] * inv_s[s];
            m.x = m.x * (1.f - w * er[s].x) + w * cd[s].x;
            m.y = m.y * (1.f - w * er[s].y) + w * cd[s].y;
            m.z = m.z * (1.f - w * er[s].z) + w * cd[s].z;
            m.w = m.w * (1.f - w * er[s].w) + w * cd[s].w;
        }

        float sv = m.x * qc.x + m.y * qc.y + m.z * qc.z + m.w * qc.w;
        sv += a4.x * qa.x + a4.y * qa.y + a4.z * qa.z + a4.w * qa.w;
        sv += __shfl_xor(sv, 1);
        sv += __shfl_xor(sv, 2);
        sv += __shfl_xor(sv, 4);
        sv += __shfl_xor(sv, 8);
        sv += __shfl_xor(sv, 16);
        float ev = __expf(beta * sv);
        if (WRITE_E && lane == 0) enew[i] = ev;
        if (lane == 0) sumloc += ev;
        acc.x += ev * m.x; acc.y += ev * m.y;
        acc.z += ev * m.z; acc.w += ev * m.w;
    }

    __shared__ float sc[8][C];
    __shared__ float ssum[256];
    *(float4*)(&sc[rg][4 * lane]) = acc;
    ssum[threadIdx.x] = sumloc;
    __syncthreads();
    if (threadIdx.x < C) {
        float v = 0.f;
#pragma unroll
        for (int g = 0; g < 8; ++g) v += sc[g][threadIdx.x];
        part[(size_t)threadIdx.x * GRID_BIG + blockIdx.x] = v;   // transposed
    }
    for (int off = 128; off > 0; off >>= 1) {
        if (threadIdx.x < off) ssum[threadIdx.x] += ssum[threadIdx.x + off];
        __syncthreads();
    }
    if (threadIdx.x == 0) part[(size_t)C * GRID_BIG + blockIdx.x] = ssum[0];
}

// ---------------------------------------------------------------------------
// Once per launch: gix = x @ W_ih[0:128] + b_ih ; candx = x @ W_cand_x ;
// plus the h0 projections (query/sharpen into qaccs slot 0).
// ---------------------------------------------------------------------------
__global__ __launch_bounds__(256) void init_k(
    const float* __restrict__ x, const float* __restrict__ h0,
    const float* __restrict__ W_ih, const float* __restrict__ b_ih,
    const float* __restrict__ W_cx,
    const float* __restrict__ W_er, const float* __restrict__ b_er,
    const float* __restrict__ W_ch, const float* __restrict__ b_cd,
    const float* __restrict__ W_q,  const float* __restrict__ b_q,
    const float* __restrict__ u_sh, const float* __restrict__ b_sh,
    float* __restrict__ gix, float* __restrict__ candx,
    float* __restrict__ eslot, float* __restrict__ cslot,
    float* __restrict__ qacc)
{
    const int tid = threadIdx.x;
    const bool b0 = (blockIdx.x == 0);
    // --- x projections (k-slice of 8 over X=128) ---
    {
        float a0 = 0.f, a1 = 0.f, a2 = 0.f, ac = 0.f;
        const int k0 = blockIdx.x * 8;
        for (int k = k0; k < k0 + 8; ++k) {
            float xk = x[k];
            const float* row = W_ih + (size_t)k * G3;
            a0 += xk * row[tid];
            a1 += xk * row[256 + tid];
            a2 += xk * row[512 + tid];
            if (tid < C) ac += xk * W_cx[k * C + tid];
        }
        atomicAdd(gix + tid,        a0 + (b0 ? b_ih[tid] : 0.f));
        atomicAdd(gix + 256 + tid,  a1 + (b0 ? b_ih[256 + tid] : 0.f));
        atomicAdd(gix + 512 + tid,  a2 + (b0 ? b_ih[512 + tid] : 0.f));
        if (tid < C) atomicAdd(candx + tid, ac);
    }
    // --- h0 projections (k-slice of 16 over H=256); eslot/cslot slot 0 is dead
    //     (only query/sharpen are consumed for step 1) but kept for generality ---
    {
        float ae = 0.f, ac2 = 0.f, aq = 0.f, ab = 0.f;
        const int k0 = blockIdx.x * 16;
        for (int k = k0; k < k0 + 16; ++k) {
            float hk = h0[k];
            if (tid < C)  { ae += hk * W_er[k * C + tid]; ac2 += hk * W_ch[k * C + tid]; }
            if (tid < AC)   aq += hk * W_q[k * AC + tid];
            if (tid == 255) ab += hk * u_sh[k];
        }
        if (tid < C) {
            atomicAdd(eslot + tid, ae + (b0 ? b_er[tid] : 0.f));
            atomicAdd(cslot + tid, ac2 + (b0 ? b_cd[tid] : 0.f));
        }
        if (tid < AC)   atomicAdd(qacc + tid, aq + (b0 ? b_q[tid] : 0.f));
        if (tid == 255) atomicAdd(qacc + AC, ab + (b0 ? b_sh[0] : 0.f));
    }
}

// ---------------------------------------------------------------------------
// Per step, fused: (A) reduce the transposed part columns this block owns
// (j = blockIdx, blockIdx+16, ...), keeping its own UNNORMALIZED content
// values in LDS; (B) gate partials -- content-gi from own columns (deferred
// normalization), gh from hprev k-slice; (C) last-arriving block combines,
// applies GRU -> hout, then computes next-step projections (post) itself
// with plain stores. One kernel replaces reduce_part + gatesfin + post.
// ---------------------------------------------------------------------------
__global__ __launch_bounds__(256) void step_fin(
    const float* __restrict__ part, float* __restrict__ craw,
    float* __restrict__ ssum4, int step,
    const float* __restrict__ hprev,
    const float* __restrict__ W_ih, const float* __restrict__ W_hh,
    const float* __restrict__ b_hh, const float* __restrict__ gix,
    float* __restrict__ p2, float* __restrict__ hout,
    const float* __restrict__ W_er, const float* __restrict__ b_er,
    const float* __restrict__ W_ch, const float* __restrict__ b_cd,
    const float* __restrict__ W_q,  const float* __restrict__ b_q,
    const float* __restrict__ u_sh, const float* __restrict__ b_sh,
    const float* __restrict__ candx,
    float* __restrict__ eslot, float* __restrict__ cslot,
    float* __restrict__ qnext,
    unsigned* __restrict__ counter, int do_post)
{
    const int tid = threadIdx.x;
    __shared__ float scol[4];
    __shared__ float myc[9];   // this block's reduced (unnormalized, unscaled) content cols

    // Phase A: reduce part[j][0..1023] for j = blockIdx, blockIdx+16, ...
    for (int j = blockIdx.x; j < C + 1; j += 16) {
        float v = 0.f;
        for (int b = tid; b < GRID_BIG; b += 256) v += part[(size_t)j * GRID_BIG + b];
        v += __shfl_xor(v, 1);  v += __shfl_xor(v, 2);  v += __shfl_xor(v, 4);
        v += __shfl_xor(v, 8);  v += __shfl_xor(v, 16); v += __shfl_xor(v, 32);
        if ((tid & 63) == 0) scol[tid >> 6] = v;
        __syncthreads();
        if (tid == 0) {
            float sv = scol[0] + scol[1] + scol[2] + scol[3];
            if (j < C) myc[(j - blockIdx.x) >> 4] = sv * MINV;   // undo x64 scale
            else       { craw[C] = sv; ssum4[step] = sv; }       // j==128 -> block 0
        }
        __syncthreads();
    }

    // Phase B: gate partials. Content-gi uses this block's own columns,
    // normalization by 1/denominator deferred to the combine.
    {
        float gi0 = 0.f, gi1 = 0.f, gi2 = 0.f;
        int idx = 0;
        for (int j = blockIdx.x; j < C; j += 16, ++idx) {
            float ck = myc[idx];
            const float* row = W_ih + (size_t)(X + j) * G3;
            gi0 += ck * row[tid]; gi1 += ck * row[256 + tid]; gi2 += ck * row[512 + tid];
        }
        float gh0 = 0.f, gh1 = 0.f, gh2 = 0.f;
        const int kh0 = blockIdx.x * 16;
        for (int k = kh0; k < kh0 + 16; ++k) {
            float hk = hprev[k];
            const float* row = W_hh + (size_t)k * G3;
            gh0 += hk * row[tid]; gh1 += hk * row[256 + tid]; gh2 += hk * row[512 + tid];
        }
        float* pb = p2 + blockIdx.x * 1536;
        pb[tid]        = gi0;
        pb[256 + tid]  = gi1;
        pb[512 + tid]  = gi2;
        pb[768 + tid]  = gh0;
        pb[1024 + tid] = gh1;
        pb[1280 + tid] = gh2;
    }

    __threadfence();
    __syncthreads();
    __shared__ int lastBlk;
    if (tid == 0) lastBlk = (atomicAdd(counter, 1u) == 15u) ? 1 : 0;
    __syncthreads();
    if (!lastBlk) return;
    __threadfence();

    // Phase C (last block): combine partials, GRU, write hout.
    float giA = 0.f, giB = 0.f, giC = 0.f, ghA = 0.f, ghB = 0.f, ghC = 0.f;
    for (int b = 0; b < 16; ++b) {
        const float* q = p2 + b * 1536;
        giA += q[tid];       giB += q[256 + tid];  giC += q[512 + tid];
        ghA += q[768 + tid]; ghB += q[1024 + tid]; ghC += q[1280 + tid];
    }
    const float inv = 1.0f / craw[C];
    float ir  = giA * inv + gix[tid];
    float iz  = giB * inv + gix[256 + tid];
    float in_ = giC * inv + gix[512 + tid];
    float hr  = ghA + b_hh[tid];
    float hz  = ghB + b_hh[256 + tid];
    float hn  = ghC + b_hh[512 + tid];
    float r = sigmoidf_(ir + hr);
    float z = sigmoidf_(iz + hz);
    float n = tanhf(in_ + r * hn);
    float h = (1.f - z) * n + z * hprev[tid];
    hout[tid] = h;
    if (!do_post) return;

    // Phase D (last block): next-step projections, plain stores (no atomics).
    __shared__ float hsh[H];
    hsh[tid] = h;
    __syncthreads();
    float ae = 0.f, ac = 0.f, aq = 0.f, ab = 0.f;
    for (int k = 0; k < H; ++k) {
        float hk = hsh[k];
        if (tid < C)  { ae += hk * W_er[k * C + tid]; ac += hk * W_ch[k * C + tid]; }
        if (tid < AC)   aq += hk * W_q[k * AC + tid];
        if (tid == 255) ab += hk * u_sh[k];
    }
    if (tid < C) {
        eslot[tid] = ae + b_er[tid];
        cslot[tid] = ac + candx[tid] + b_cd[tid];
    }
    if (tid < AC)   qnext[tid] = aq + b_q[tid];
    if (tid == 255) qnext[AC]  = ab + b_sh[0];
}

extern "C" void kernel_launch(void* const* d_in, const int* in_sizes, int n_in,
                              void* d_out, int out_size, void* d_ws, size_t ws_size,
                              hipStream_t stream) {
    (void)in_sizes; (void)n_in; (void)out_size; (void)ws_size;
    const float* x    = (const float*)d_in[0];
    const float* h0   = (const float*)d_in[1];
    const float* mem0 = (const float*)d_in[2];   // read-only
    const float* addr = (const float*)d_in[3];
    const float* W_q  = (const float*)d_in[4];
    const float* b_q  = (const float*)d_in[5];
    const float* u_sh = (const float*)d_in[6];
    const float* b_sh = (const float*)d_in[7];
    const float* W_er = (const float*)d_in[8];
    const float* b_er = (const float*)d_in[9];
    const float* W_ch = (const float*)d_in[10];
    const float* W_cx = (const float*)d_in[11];
    const float* b_cd = (const float*)d_in[12];
    const float* W_ih = (const float*)d_in[13];
    const float* W_hh = (const float*)d_in[14];
    const float* b_ih = (const float*)d_in[15];
    const float* b_hh = (const float*)d_in[16];
    float* hout = (float*)d_out;

    // workspace layout (~95 MB):
    float*    e      = (float*)d_ws;                           // [3][N_LOC] fp32
    uchar_t*  memq   = (uchar_t*)(e + 3 * N_LOC);              // [N_LOC][C] fp8 (x64)
    ushort_t* addrbf = (ushort_t*)(memq + (size_t)N_LOC * C);  // [N_LOC][A] bf16
    float*    part   = (float*)(addrbf + (size_t)N_LOC * A);   // [132][GRID_BIG] transposed
    float*    p2     = part + 132 * GRID_BIG;                  // [16][1536]
    float*    craw   = p2 + 16 * 1536;                         // [132] (only [128] used)
    float*    S0     = craw + 132;                             // zeroed region:
    float*    gix    = S0;                                     // [768]
    float*    candx  = S0 + 768;                               // [128]
    float*    qaccs  = S0 + 896;                               // [5][160] (153 used/slot)
    float*    ehist  = S0 + 1696;                              // [5][128]
    float*    chist  = S0 + 2336;                              // [5][128]
    float*    ssum4  = S0 + 2976;                              // [8]
    unsigned* cnt    = (unsigned*)(S0 + 2984);                 // [16] counters

    hipMemsetAsync(S0, 0, 3000 * sizeof(float), stream);
    init_k<<<16, 256, 0, stream>>>(x, h0, W_ih, b_ih, W_cx, W_er, b_er, W_ch, b_cd,
                                   W_q, b_q, u_sh, b_sh, gix, candx, ehist, chist, qaccs);
    // step 1 (also emits fp8/bf16 copies of mem0/addr)
    big_pass<0, true, true><<<GRID_BIG, 256, 0, stream>>>(
        mem0, addr, memq, addrbf, qaccs, ehist, chist, ssum4, e, e, part);
    step_fin<<<16, 256, 0, stream>>>(part, craw, ssum4, 1, h0, W_ih, W_hh, b_hh, gix,
        p2, hout, W_er, b_er, W_ch, b_cd, W_q, b_q, u_sh, b_sh, candx,
        ehist + C, chist + C, qaccs + 160, cnt + 0, 1);
    // step 2
    big_pass<1, true, false><<<GRID_BIG, 256, 0, stream>>>(
        mem0, addr, memq, addrbf, qaccs + 160, ehist, chist, ssum4, e, e + N_LOC, part);
    step_fin<<<16, 256, 0, stream>>>(part, craw, ssum4, 2, hout, W_ih, W_hh, b_hh, gix,
        p2, hout, W_er, b_er, W_ch, b_cd, W_q, b_q, u_sh, b_sh, candx,
        ehist + 2 * C, chist + 2 * C, qaccs + 320, cnt + 1, 1);
    // step 3
    big_pass<2, true, false><<<GRID_BIG, 256, 0, stream>>>(
        mem0, addr, memq, addrbf, qaccs + 320, ehist, chist, ssum4, e, e + 2 * N_LOC, part);
    step_fin<<<16, 256, 0, stream>>>(part, craw, ssum4, 3, hout, W_ih, W_hh, b_hh, gix,
        p2, hout, W_er, b_er, W_ch, b_cd, W_q, b_q, u_sh, b_sh, candx,
        ehist + 3 * C, chist + 3 * C, qaccs + 480, cnt + 2, 1);
    // step 4 (no e write, no next-step projections)
    big_pass<3, false, false><<<GRID_BIG, 256, 0, stream>>>(
        mem0, addr, memq, addrbf, qaccs + 480, ehist, chist, ssum4, e, e, part);
    step_fin<<<16, 256, 0, stream>>>(part, craw, ssum4, 4, hout, W_ih, W_hh, b_hh, gix,
        p2, hout, W_er, b_er, W_ch, b_cd, W_q, b_q, u_sh, b_sh, candx,
        ehist + 4 * C, chist + 4 * C, qaccs + 640, cnt + 3, 0);
}

// Round 2
// 736.498 us; speedup vs baseline: 1.6597x; 1.6597x over previous
//
#include <hip/hip_runtime.h>

#define N_LOC 500000
#define C 128
#define A 24
#define AC 152          // A + C
#define H 256
#define X 128
#define G3 768          // 3*H
#define GRID_BIG 1024
#define MSCALE 64.0f    // contents stored as fp8(e4m3) of 64*value (dodges denorm cliff)
#define MINV 0.015625f  // 1/64

typedef unsigned short ushort_t;
typedef unsigned char uchar_t;
typedef float floatx2 __attribute__((ext_vector_type(2)));

__device__ __forceinline__ float sigmoidf_(float x) { return 1.0f / (1.0f + __expf(-x)); }

// bf16 pack/unpack (RNE; inputs finite) -- used for addresses
__device__ __forceinline__ ushort_t f2bf(float f) {
    unsigned u = __float_as_uint(f);
    u += 0x7FFFu + ((u >> 16) & 1u);
    return (ushort_t)(u >> 16);
}
__device__ __forceinline__ float bf2f(ushort_t s) {
    return __uint_as_float(((unsigned)s) << 16);
}

// ---- OCP e4m3fn helpers (HW cvt if available, bit-exact SW fallback) ----
#if defined(__has_builtin)
#if __has_builtin(__builtin_amdgcn_cvt_pk_fp8_f32) && __has_builtin(__builtin_amdgcn_cvt_pk_f32_fp8)
#define HAVE_HW_FP8 1
#endif
#endif

__device__ __forceinline__ unsigned f2fp8_sw(float f) {   // RNE encode, pre-scaled input
    unsigned sgn = (__float_as_uint(f) >> 24) & 0x80u;
    float af = fminf(fabsf(f), 448.0f);
    unsigned q;
    if (af < 0.015625f) {                       // denormal band: round(v*512), 8 rolls into min-normal
        q = (unsigned)__float2int_rn(af * 512.0f);
    } else {
        unsigned a = __float_as_uint(af);
        a += 0x7FFFFu + ((a >> 20) & 1u);       // RNE into 3-bit mantissa
        unsigned e = (a >> 23) - 120u;
        q = (e << 3) | ((a >> 20) & 7u);
        if (q > 126u) q = 126u;                 // clamp at 448, never emit NaN code
    }
    return q | sgn;
}
__device__ __forceinline__ float fp8d_sw(unsigned b) {
    unsigned sgn = (b & 0x80u) << 24;
    unsigned e = (b >> 3) & 15u;
    unsigned m = b & 7u;
    float fn = __uint_as_float(sgn | ((e + 120u) << 23) | (m << 20));
    float fd = __uint_as_float(sgn | __float_as_uint((float)m * 0.001953125f));
    return e ? fn : fd;
}
__device__ __forceinline__ unsigned pack_fp8x4(float4 m) {
#ifdef HAVE_HW_FP8
    int w = 0;
    w = __builtin_amdgcn_cvt_pk_fp8_f32(m.x, m.y, w, false);
    w = __builtin_amdgcn_cvt_pk_fp8_f32(m.z, m.w, w, true);
    return (unsigned)w;
#else
    return f2fp8_sw(m.x) | (f2fp8_sw(m.y) << 8) | (f2fp8_sw(m.z) << 16) | (f2fp8_sw(m.w) << 24);
#endif
}
__device__ __forceinline__ float4 unpack_fp8x4(unsigned w) {
#ifdef HAVE_HW_FP8
    floatx2 lo = __builtin_amdgcn_cvt_pk_f32_fp8((int)w, false);
    floatx2 hi = __builtin_amdgcn_cvt_pk_f32_fp8((int)w, true);
    return make_float4(lo[0], lo[1], hi[0], hi[1]);
#else
    return make_float4(fp8d_sw(w & 255u), fp8d_sw((w >> 8) & 255u),
                       fp8d_sw((w >> 16) & 255u), fp8d_sw(w >> 24));
#endif
}

// ---------------------------------------------------------------------------
// Big streaming pass over N_LOC x C memory. Contents cached as fp8 (x64
// scaled domain), addresses as bf16. mem_t recomputed on the fly from the
// pristine cached copy + per-step scalars. part is TRANSPOSED: [132][1024]
// so the reducer reads it coalesced. Content partials are in the x64 domain;
// the denominator row (j==C) is unscaled.
// ---------------------------------------------------------------------------
template <int NPREV, bool WRITE_E, bool CONVERT>
__global__ __launch_bounds__(256) void big_pass(
    const float* __restrict__ mem0, const float* __restrict__ addr,
    uchar_t* __restrict__ memq, ushort_t* __restrict__ addrbf,
    const float* __restrict__ qacc,   // [153]: q[0..151], raw sharpen at [152]
    const float* __restrict__ ehist,  // [4][128] raw erase pre-sigmoid
    const float* __restrict__ chist,  // [4][128] raw cand pre-relu
    const float* __restrict__ ssum4,  // [8]: softmax denom of step s
    const float* __restrict__ earr,   // [3][N_LOC] raw exp values per step
    float* __restrict__ enew,         // e output for this step (if WRITE_E)
    float* __restrict__ part)         // [132][GRID_BIG] partials (content rows | denom row)
{
    const int lane = threadIdx.x & 31;   // column group: 4 elements each
    const int rg   = threadIdx.x >> 5;   // row group 0..7

    float4 qc = *(const float4*)(qacc + A + 4 * lane);
    qc.x *= MINV; qc.y *= MINV; qc.z *= MINV; qc.w *= MINV;  // fold 1/64 (m is x64)
    float4 qa = make_float4(0.f, 0.f, 0.f, 0.f);
    if (lane < 6) qa = *(const float4*)(qacc + 4 * lane);
    float beta;
    { float t = qacc[AC]; beta = (t > 20.f ? t : log1pf(__expf(t))) + 1.0f; }

    constexpr int NP = (NPREV > 0) ? NPREV : 1;
    float4 er[NP], cd[NP];
    float inv_s[NP];
#pragma unroll
    for (int s = 0; s < NPREV; ++s) {
        float4 et = *(const float4*)(ehist + (s + 1) * C + 4 * lane);
        er[s].x = sigmoidf_(et.x); er[s].y = sigmoidf_(et.y);
        er[s].z = sigmoidf_(et.z); er[s].w = sigmoidf_(et.w);
        float4 ct = *(const float4*)(chist + (s + 1) * C + 4 * lane);
        cd[s].x = fmaxf(ct.x, 0.f) * MSCALE;  // cand in scaled domain
        cd[s].y = fmaxf(ct.y, 0.f) * MSCALE;
        cd[s].z = fmaxf(ct.z, 0.f) * MSCALE;
        cd[s].w = fmaxf(ct.w, 0.f) * MSCALE;
        inv_s[s] = 1.0f / ssum4[s + 1];
    }

    float4 acc = make_float4(0.f, 0.f, 0.f, 0.f);
    float sumloc = 0.f;
    const int stride = gridDim.x * 8;

    for (int i = blockIdx.x * 8 + rg; i < N_LOC; i += stride) {
        float4 m, a4 = make_float4(0.f, 0.f, 0.f, 0.f);
        if (CONVERT) {
            float4 mf = *(const float4*)(mem0 + (size_t)i * C + 4 * lane);
            m.x = mf.x * MSCALE; m.y = mf.y * MSCALE;
            m.z = mf.z * MSCALE; m.w = mf.w * MSCALE;
            *(unsigned*)(memq + (size_t)i * C + 4 * lane) = pack_fp8x4(m);
            if (lane < 6) {
                a4 = *(const float4*)(addr + (size_t)i * A + 4 * lane);
                ushort4 au; au.x = f2bf(a4.x); au.y = f2bf(a4.y);
                au.z = f2bf(a4.z); au.w = f2bf(a4.w);
                *(ushort4*)(addrbf + (size_t)i * A + 4 * lane) = au;
            }
        } else {
            unsigned mw = *(const unsigned*)(memq + (size_t)i * C + 4 * lane);
            m = unpack_fp8x4(mw);  // scaled domain (64x)
            if (lane < 6) {
                ushort4 au = *(const ushort4*)(addrbf + (size_t)i * A + 4 * lane);
                a4 = make_float4(bf2f(au.x), bf2f(au.y), bf2f(au.z), bf2f(au.w));
            }
        }

#pragma unroll
        for (int s = 0; s < NPREV; ++s) {
            float w = earr[s * N_LOC + i] * inv_s[s];
            m.x = m.x * (1.f - w * er[s].x) + w * cd[s].x;
            m.y = m.y * (1.f - w * er[s].y) + w * cd[s].y;
            m.z = m.z * (1.f - w * er[s].z) + w * cd[s].z;
            m.w = m.w * (1.f - w * er[s].w) + w * cd[s].w;
        }

        float sv = m.x * qc.x + m.y * qc.y + m.z * qc.z + m.w * qc.w;
        sv += a4.x * qa.x + a4.y * qa.y + a4.z * qa.z + a4.w * qa.w;
        sv += __shfl_xor(sv, 1);
        sv += __shfl_xor(sv, 2);
        sv += __shfl_xor(sv, 4);
        sv += __shfl_xor(sv, 8);
        sv += __shfl_xor(sv, 16);
        float ev = __expf(beta * sv);
        if (WRITE_E && lane == 0) enew[i] = ev;
        if (lane == 0) sumloc += ev;
        acc.x += ev * m.x; acc.y += ev * m.y;
        acc.z += ev * m.z; acc.w += ev * m.w;
    }

    __shared__ float sc[8][C];
    __shared__ float ssum[256];
    *(float4*)(&sc[rg][4 * lane]) = acc;
    ssum[threadIdx.x] = sumloc;
    __syncthreads();
    if (threadIdx.x < C) {
        float v = 0.f;
#pragma unroll
        for (int g = 0; g < 8; ++g) v += sc[g][threadIdx.x];
        part[(size_t)threadIdx.x * GRID_BIG + blockIdx.x] = v;   // transposed
    }
    for (int off = 128; off > 0; off >>= 1) {
        if (threadIdx.x < off) ssum[threadIdx.x] += ssum[threadIdx.x + off];
        __syncthreads();
    }
    if (threadIdx.x == 0) part[(size_t)C * GRID_BIG + blockIdx.x] = ssum[0];
}

// ---------------------------------------------------------------------------
// Reduce transposed part [132][1024] -> craw[0..128]; coalesced inner loop.
// 129 blocks, one column each. Records softmax denominator at j==C.
// ---------------------------------------------------------------------------
__global__ __launch_bounds__(256) void reduce_part(
    const float* __restrict__ part, float* __restrict__ craw,
    float* __restrict__ ssum4, int step)
{
    const int j = blockIdx.x;           // 0..128
    float v = 0.f;
    for (int b = threadIdx.x; b < GRID_BIG; b += 256)
        v += part[(size_t)j * GRID_BIG + b];
    __shared__ float sh[256];
    sh[threadIdx.x] = v;
    __syncthreads();
    for (int off = 128; off > 0; off >>= 1) {
        if (threadIdx.x < off) sh[threadIdx.x] += sh[threadIdx.x + off];
        __syncthreads();
    }
    if (threadIdx.x == 0) {
        craw[j] = sh[0];
        if (j == C) ssum4[step] = sh[0];
    }
}

// ---------------------------------------------------------------------------
// Once per launch: gix = x @ W_ih[0:128] + b_ih ; candx = x @ W_cand_x
// ---------------------------------------------------------------------------
__global__ __launch_bounds__(256) void prex(
    const float* __restrict__ x, const float* __restrict__ W_ih,
    const float* __restrict__ b_ih, const float* __restrict__ W_cx,
    float* __restrict__ gix, float* __restrict__ candx)
{
    const int tid = threadIdx.x;
    float a0 = 0.f, a1 = 0.f, a2 = 0.f, ac = 0.f;
    const int k0 = blockIdx.x * 8;
    for (int k = k0; k < k0 + 8; ++k) {
        float xk = x[k];
        const float* row = W_ih + (size_t)k * G3;
        a0 += xk * row[tid];
        a1 += xk * row[256 + tid];
        a2 += xk * row[512 + tid];
        if (tid < C) ac += xk * W_cx[k * C + tid];
    }
    const bool b0 = (blockIdx.x == 0);
    atomicAdd(gix + tid,        a0 + (b0 ? b_ih[tid] : 0.f));
    atomicAdd(gix + 256 + tid,  a1 + (b0 ? b_ih[256 + tid] : 0.f));
    atomicAdd(gix + 512 + tid,  a2 + (b0 ? b_ih[512 + tid] : 0.f));
    if (tid < C) atomicAdd(candx + tid, ac);
}

// ---------------------------------------------------------------------------
// Per step: raw erase/cand/query/sharpen projections from h. 16 k-sliced
// blocks so the W reads have chip-wide parallelism (latency-bound region).
// ---------------------------------------------------------------------------
__global__ __launch_bounds__(256) void post(
    const float* __restrict__ h,
    const float* __restrict__ W_er, const float* __restrict__ b_er,
    const float* __restrict__ W_ch, const float* __restrict__ b_cd,
    const float* __restrict__ W_q,  const float* __restrict__ b_q,
    const float* __restrict__ u_sh, const float* __restrict__ b_sh,
    const float* __restrict__ candx,
    float* __restrict__ eslot, float* __restrict__ cslot,
    float* __restrict__ qacc)
{
    const int tid = threadIdx.x;
    float ae = 0.f, ac = 0.f, aq = 0.f, ab = 0.f;
    const int k0 = blockIdx.x * 16;
    for (int k = k0; k < k0 + 16; ++k) {
        float hk = h[k];
        if (tid < C)  { ae += hk * W_er[k * C + tid]; ac += hk * W_ch[k * C + tid]; }
        if (tid < AC)   aq += hk * W_q[k * AC + tid];
        if (tid == 255) ab += hk * u_sh[k];
    }
    const bool b0 = (blockIdx.x == 0);
    if (tid < C) {
        atomicAdd(eslot + tid, ae + (b0 ? b_er[tid] : 0.f));
        atomicAdd(cslot + tid, ac + (b0 ? (candx[tid] + b_cd[tid]) : 0.f));
    }
    if (tid < AC)   atomicAdd(qacc + tid, aq + (b0 ? b_q[tid] : 0.f));
    if (tid == 255) atomicAdd(qacc + AC, ab + (b0 ? b_sh[0] : 0.f));
}

// ---------------------------------------------------------------------------
// Per step: GRU gate partials (16 k-sliced blocks) + last-arriving block
// reduces and applies the GRU combine -> hout. Zeroes qacc, resets counter.
// Content values come from craw in the x64 domain: fold MINV into inv.
// ---------------------------------------------------------------------------
__global__ __launch_bounds__(256) void gatesfin(
    const float* __restrict__ craw, const float* __restrict__ hprev,
    const float* __restrict__ W_ih, const float* __restrict__ W_hh,
    const float* __restrict__ b_hh, const float* __restrict__ gix,
    float* __restrict__ p2, float* __restrict__ hout,
    float* __restrict__ qacc, unsigned* __restrict__ counter)
{
    const int tid = threadIdx.x;
    const float inv = MINV / craw[C];   // undo x64 scale + softmax normalize
    float gi0 = 0.f, gi1 = 0.f, gi2 = 0.f, gh0 = 0.f, gh1 = 0.f, gh2 = 0.f;
    const int kc0 = blockIdx.x * 8;
    for (int k = kc0; k < kc0 + 8; ++k) {
        float ck = craw[k] * inv;                       // content[k]
        const float* row = W_ih + (size_t)(X + k) * G3;
        gi0 += ck * row[tid]; gi1 += ck * row[256 + tid]; gi2 += ck * row[512 + tid];
    }
    const int kh0 = blockIdx.x * 16;
    for (int k = kh0; k < kh0 + 16; ++k) {
        float hk = hprev[k];
        const float* row = W_hh + (size_t)k * G3;
        gh0 += hk * row[tid]; gh1 += hk * row[256 + tid]; gh2 += hk * row[512 + tid];
    }
    const bool b0 = (blockIdx.x == 0);
    float* pb = p2 + blockIdx.x * 1536;
    pb[tid]        = gi0 + (b0 ? gix[tid] : 0.f);
    pb[256 + tid]  = gi1 + (b0 ? gix[256 + tid] : 0.f);
    pb[512 + tid]  = gi2 + (b0 ? gix[512 + tid] : 0.f);
    pb[768 + tid]  = gh0 + (b0 ? b_hh[tid] : 0.f);
    pb[1024 + tid] = gh1 + (b0 ? b_hh[256 + tid] : 0.f);
    pb[1280 + tid] = gh2 + (b0 ? b_hh[512 + tid] : 0.f);
    __threadfence();
    __syncthreads();
    __shared__ int lastBlk;
    if (tid == 0) lastBlk = (atomicAdd(counter, 1u) == 15u) ? 1 : 0;
    __syncthreads();
    if (!lastBlk) return;
    __threadfence();
    float ir = 0.f, iz = 0.f, in_ = 0.f, hr = 0.f, hz = 0.f, hn = 0.f;
    for (int b = 0; b < 16; ++b) {
        const float* q = p2 + b * 1536;
        ir += q[tid]; iz += q[256 + tid]; in_ += q[512 + tid];
        hr += q[768 + tid]; hz += q[1024 + tid]; hn += q[1280 + tid];
    }
    float r = sigmoidf_(ir + hr);
    float z = sigmoidf_(iz + hz);
    float n = tanhf(in_ + r * hn);
    hout[tid] = (1.f - z) * n + z * hprev[tid];
    if (tid < 160) qacc[tid] = 0.f;
    if (tid == 0) *counter = 0u;
}

extern "C" void kernel_launch(void* const* d_in, const int* in_sizes, int n_in,
                              void* d_out, int out_size, void* d_ws, size_t ws_size,
                              hipStream_t stream) {
    (void)in_sizes; (void)n_in; (void)out_size; (void)ws_size;
    const float* x    = (const float*)d_in[0];
    const float* h0   = (const float*)d_in[1];
    const float* mem0 = (const float*)d_in[2];   // read-only
    const float* addr = (const float*)d_in[3];
    const float* W_q  = (const float*)d_in[4];
    const float* b_q  = (const float*)d_in[5];
    const float* u_sh = (const float*)d_in[6];
    const float* b_sh = (const float*)d_in[7];
    const float* W_er = (const float*)d_in[8];
    const float* b_er = (const float*)d_in[9];
    const float* W_ch = (const float*)d_in[10];
    const float* W_cx = (const float*)d_in[11];
    const float* b_cd = (const float*)d_in[12];
    const float* W_ih = (const float*)d_in[13];
    const float* W_hh = (const float*)d_in[14];
    const float* b_ih = (const float*)d_in[15];
    const float* b_hh = (const float*)d_in[16];
    float* hout = (float*)d_out;

    // workspace layout (~95 MB):
    float*    e      = (float*)d_ws;                           // [3][N_LOC] fp32
    uchar_t*  memq   = (uchar_t*)(e + 3 * N_LOC);              // [N_LOC][C] fp8 (x64)
    ushort_t* addrbf = (ushort_t*)(memq + (size_t)N_LOC * C);  // [N_LOC][A] bf16
    float*    part   = (float*)(addrbf + (size_t)N_LOC * A);   // [132][GRID_BIG] transposed
    float*    S      = part + 132 * GRID_BIG;
    float*    craw   = S;                                      // [144]
    float*    qacc   = S + 144;                                // [160] (153 used)
    float*    ehist  = S + 304;                                // [4][128]
    float*    chist  = S + 816;                                // [4][128]
    float*    gix    = S + 1328;                               // [768]
    float*    candx  = S + 2096;                               // [128]
    float*    ssum4  = S + 2224;                               // [8]
    unsigned* counter= (unsigned*)(S + 2232);                  // [1] (+pad)
    float*    p2     = S + 2240;                               // [16][1536]

    hipMemsetAsync(S, 0, 2240 * sizeof(float), stream);
    prex<<<16, 256, 0, stream>>>(x, W_ih, b_ih, W_cx, gix, candx);
    post<<<16, 256, 0, stream>>>(h0, W_er, b_er, W_ch, b_cd, W_q, b_q, u_sh, b_sh,
                                 candx, ehist, chist, qacc);
    // step 1 (also emits fp8/bf16 copies of mem0/addr)
    big_pass<0, true, true><<<GRID_BIG, 256, 0, stream>>>(
        mem0, addr, memq, addrbf, qacc, ehist, chist, ssum4, e, e, part);
    reduce_part<<<129, 256, 0, stream>>>(part, craw, ssum4, 1);
    gatesfin<<<16, 256, 0, stream>>>(craw, h0, W_ih, W_hh, b_hh, gix, p2, hout,
                                     qacc, counter);
    post<<<16, 256, 0, stream>>>(hout, W_er, b_er, W_ch, b_cd, W_q, b_q, u_sh, b_sh,
                                 candx, ehist + C, chist + C, qacc);
    // step 2
    big_pass<1, true, false><<<GRID_BIG, 256, 0, stream>>>(
        mem0, addr, memq, addrbf, qacc, ehist, chist, ssum4, e, e + N_LOC, part);
    reduce_part<<<129, 256, 0, stream>>>(part, craw, ssum4, 2);
    gatesfin<<<16, 256, 0, stream>>>(craw, hout, W_ih, W_hh, b_hh, gix, p2, hout,
                                     qacc, counter);
    post<<<16, 256, 0, stream>>>(hout, W_er, b_er, W_ch, b_cd, W_q, b_q, u_sh, b_sh,
                                 candx, ehist + 2 * C, chist + 2 * C, qacc);
    // step 3
    big_pass<2, true, false><<<GRID_BIG, 256, 0, stream>>>(
        mem0, addr, memq, addrbf, qacc, ehist, chist, ssum4, e, e + 2 * N_LOC, part);
    reduce_part<<<129, 256, 0, stream>>>(part, craw, ssum4, 3);
    gatesfin<<<16, 256, 0, stream>>>(craw, hout, W_ih, W_hh, b_hh, gix, p2, hout,
                                     qacc, counter);
    post<<<16, 256, 0, stream>>>(hout, W_er, b_er, W_ch, b_cd, W_q, b_q, u_sh, b_sh,
                                 candx, ehist + 3 * C, chist + 3 * C, qacc);
    // step 4 (no memory write-back needed; e not stored)
    big_pass<3, false, false><<<GRID_BIG, 256, 0, stream>>>(
        mem0, addr, memq, addrbf, qacc, ehist, chist, ssum4, e, e, part);
    reduce_part<<<129, 256, 0, stream>>>(part, craw, ssum4, 4);
    gatesfin<<<16, 256, 0, stream>>>(craw, hout, W_ih, W_hh, b_hh, gix, p2, hout,
                                     qacc, counter);
}